// Round 6
// baseline (180.045 us; speedup 1.0000x reference)
//
#include <hip/hip_runtime.h>
#include <cstdint>
#include <cstddef>

// ---------- types ----------
typedef __bf16 bf16_t;
typedef __bf16 bf16x8 __attribute__((ext_vector_type(8)));
typedef __bf16 bf16x4 __attribute__((ext_vector_type(4)));
typedef float  f32x4  __attribute__((ext_vector_type(4)));
typedef unsigned int u32x2 __attribute__((ext_vector_type(2)));
typedef unsigned int u32x4 __attribute__((ext_vector_type(4)));

#define MFMA_BF16(a, b, c) __builtin_amdgcn_mfma_f32_16x16x32_bf16((a), (b), (c), 0, 0, 0)

// async global->LDS, 16B per lane. LDS dest must be wave-uniform base + lane*16.
__device__ __forceinline__ void async_load16(const void* g, void* l) {
    __builtin_amdgcn_global_load_lds((const __attribute__((address_space(1))) void*)g,
                                     (__attribute__((address_space(3))) void*)l,
                                     16, 0, 0);
}

// XOR-swizzled LDS layout for tiles with 8 16B-chunks per row (64 bf16/row).
// chunk (r, cg) lives at slot r*8 + (cg ^ (r&7)); returns bf16 element offset.
#define SWZ(r, cg) ((((r) << 3) | ((cg) ^ ((r) & 7))) << 3)

// ---------- problem constants ----------
#define Bq   2
#define Tq   2048
#define Cq   1024
#define Hq   16
#define HSq  64
#define Mrows 4096   // B*T

// softplus scale folded into Q at the gemm1 epilogue: 0.125 * log2(e)
#define QSCALE 0.18033688f

// ---------- fused fp32 -> bf16 convert for x, W_qkv, W_proj ----------
__global__ __launch_bounds__(256)
void cvt_all(const float* __restrict__ x, const float* __restrict__ wqkv,
             const float* __restrict__ wproj,
             bf16_t* __restrict__ xb, bf16_t* __restrict__ wqkvb,
             bf16_t* __restrict__ wprojb) {
    size_t gid = (size_t)blockIdx.x * 256 + threadIdx.x;  // quad index
    const float* src; bf16_t* dst; size_t off;
    if (gid < 1048576)      { src = x;     dst = xb;     off = gid; }
    else if (gid < 1835008) { src = wqkv;  dst = wqkvb;  off = gid - 1048576; }
    else                    { src = wproj; dst = wprojb; off = gid - 1835008; }
    float4 v = ((const float4*)src)[off];
    bf16x4 o;
    o[0] = (bf16_t)v.x; o[1] = (bf16_t)v.y; o[2] = (bf16_t)v.z; o[3] = (bf16_t)v.w;
    *(bf16x4*)(dst + off * 4) = o;
}

// ---------- GEMM: C[m][n] = sum_k A[m][k]*B[n][k], A:[M,K], B:[N,K] row-major ----------
// BK=64, XOR-swizzled LDS. EPI=1: fp32 out + bias. EPI=2: QKV split epilogue.
// DBUF=0: classic 2-barrier loop — needs >= 2 blocks/CU to hide the vmcnt(0)
//   barrier drain (R10 post-mortem: BM=128 grid 256 = 1/CU exposed it, +4.6us).
// DBUF=1: minimum-2-phase pipeline (T3 recipe, m230/m248): double-buffered LDS,
//   STAGE(next) issued BEFORE compute(cur), ONE __syncthreads per K-step placed
//   after the MFMAs. Load latency (~250cy L2) covered by compute (~360cy), so
//   1 block/CU no longer stalls. WAR safety: STAGE into buf b at step t is
//   preceded by barrier(t-1) whose lgkmcnt(0) drain covers all reads of buf b.
template <int BM, int EPI, int DBUF>
__global__ __launch_bounds__(256)
void gemm_bt(const bf16_t* __restrict__ A, const bf16_t* __restrict__ B,
             void* __restrict__ Cout, const float* __restrict__ bias,
             bf16_t* __restrict__ qc, bf16_t* __restrict__ kc, bf16_t* __restrict__ vtp,
             int M, int N, int K) {
    constexpr int MR = BM / 32;        // MFMA row-tiles per wave
    constexpr int ACH = BM * 8 / 256;  // A-chunks per thread (BM=128 -> 4, 64 -> 2)
    constexpr int NB = DBUF ? 2 : 1;
    __shared__ __align__(16) bf16_t As[NB * BM * 64];
    __shared__ __align__(16) bf16_t Bs[NB * 128 * 64];

    const int tid  = threadIdx.x;
    const int wave = tid >> 6;
    const int lane = tid & 63;
    const int m0 = blockIdx.y * BM;
    const int n0 = blockIdx.x * 128;
    const int wm = (wave >> 1) * (BM / 2);
    const int wn = (wave & 1) * 64;
    const int lrow = lane & 15;
    const int lg   = lane >> 4;

    f32x4 acc[MR][4] = {};

    const bf16_t* Ag = A + (size_t)m0 * K;
    const bf16_t* Bg = B + (size_t)n0 * K;

    auto stage = [&](int buf, int k0) {
        #pragma unroll
        for (int i = 0; i < ACH; i++) {
            int s = i * 256 + tid;
            int r = s >> 3, cg = (s & 7) ^ (r & 7);
            async_load16(Ag + (size_t)r * K + k0 + cg * 8, &As[buf * (BM * 64) + s * 8]);
        }
        #pragma unroll
        for (int i = 0; i < 4; i++) {
            int s = i * 256 + tid;
            int r = s >> 3, cg = (s & 7) ^ (r & 7);
            async_load16(Bg + (size_t)r * K + k0 + cg * 8, &Bs[buf * 8192 + s * 8]);
        }
    };

    auto compute = [&](int buf) {
        const int ao = buf * (BM * 64), bo = buf * 8192;
        #pragma unroll
        for (int kk = 0; kk < 2; kk++) {
            bf16x8 af[MR], bfr[4];
            #pragma unroll
            for (int r = 0; r < MR; r++)
                af[r] = *(const bf16x8*)&As[ao + SWZ(wm + r * 16 + lrow, kk * 4 + lg)];
            #pragma unroll
            for (int c = 0; c < 4; c++)
                bfr[c] = *(const bf16x8*)&Bs[bo + SWZ(wn + c * 16 + lrow, kk * 4 + lg)];
            #pragma unroll
            for (int r = 0; r < MR; r++)
                #pragma unroll
                for (int c = 0; c < 4; c++)
                    acc[r][c] = MFMA_BF16(af[r], bfr[c], acc[r][c]);
        }
    };

    if constexpr (DBUF) {
        stage(0, 0);
        __syncthreads();          // vmcnt(0): tile 0 resident
        int cur = 0;
        for (int k0 = 0; k0 < K; k0 += 64) {
            if (k0 + 64 < K) stage(cur ^ 1, k0 + 64);  // in flight during compute
            compute(cur);
            __syncthreads();      // drains vmcnt(0) -> next tile ready; lgkm done
            cur ^= 1;
        }
    } else {
        for (int k0 = 0; k0 < K; k0 += 64) {
            stage(0, k0);
            __syncthreads();
            compute(0);
            __syncthreads();
        }
    }

    const int er = (lane >> 4) * 4;
    const int ec = lane & 15;
    #pragma unroll
    for (int r = 0; r < MR; r++) {
        #pragma unroll
        for (int c = 0; c < 4; c++) {
            int m = m0 + wm + r * 16 + er;
            int n = n0 + wn + c * 16 + ec;
            if (EPI == 1) {
                #pragma unroll
                for (int v = 0; v < 4; v++)
                    ((float*)Cout)[(size_t)(m + v) * N + n] = acc[r][c][v] + bias[n];
            } else {
                int bb = m >> 11, t = m & 2047;   // block-uniform region (n0 128-aligned)
                if (n < 1024) {
                    // pre-scale Q so attn's S == t directly (log2-domain softplus)
                    #pragma unroll
                    for (int v = 0; v < 4; v++)
                        qc[(size_t)(m + v) * 1024 + n] = (bf16_t)(acc[r][c][v] * QSCALE);
                } else if (n < 2048) {
                    int h = (n - 1024) >> 6, d = (n - 1024) & 63;
                    bf16_t* p = kc + ((size_t)(bb * 16 + h) * Tq + t) * 64 + d;
                    #pragma unroll
                    for (int v = 0; v < 4; v++) p[v * 64] = (bf16_t)acc[r][c][v];
                } else {
                    int h = (n - 2048) >> 6, d = (n - 2048) & 63;
                    bf16x4 o;
                    #pragma unroll
                    for (int v = 0; v < 4; v++) o[v] = (bf16_t)acc[r][c][v];
                    *(bf16x4*)&vtp[((size_t)(bb * 16 + h) * 64 + d) * Tq + t] = o;
                }
            }
        }
    }
}

// ---------- attention: R6 dataflow (Q=64/block, compact K/V, 4-way k-split) ----------
// R8: grid transposed (bh, raw) -> XCD = bh%8 owns 4 bh = 2MB K/V (L2-resident);
//     softplus in log2 domain with Q pre-scaled.
// R9/R10: double-buffered Ks/Vs, ONE barrier per tile; no setprio (lockstep waves).
// R11/R12: Ws LDS round-trip replaced by in-register permlane redistribution
//     (builtins, not raw asm — R4's raw asm hit unhandled VALU->permlane hazards).
// R13 note: R9..R12 attn changes all measured neutral (±1.5us) — attn is at a
//     mixed latency floor, not DS-pipe-bound as R11 theorized. Structure frozen.
__global__ __launch_bounds__(256)
void attn_kernel(const bf16_t* __restrict__ Qc, const bf16_t* __restrict__ Kc,
                 const bf16_t* __restrict__ Vt,
                 bf16_t* __restrict__ Op0, bf16_t* __restrict__ Op1,
                 bf16_t* __restrict__ Op2, bf16_t* __restrict__ Op3,
                 float* __restrict__ n2part) {
    __shared__ __align__(16) bf16_t Ks[2][64 * 64];  // swizzled [key][d], double-buffered
    __shared__ __align__(16) bf16_t Vs[2][64 * 64];  // swizzled [d][key], double-buffered

    const int tid = threadIdx.x;
    const int wave = tid >> 6;
    const int lane = tid & 63;
    const int lrow = lane & 15;
    const int lg   = lane >> 4;     // 0..3
    const int er = lg * 4;
    const int ec = lane & 15;

    const int raw     = blockIdx.y;       // 0..127, globally heavy-first
    const int qi      = 31 - (raw >> 2);
    const int quarter = raw & 3;
    const int q0      = qi * 64;
    const int bh = blockIdx.x;            // XCD = bh % 8 -> per-XCD K/V = 4 bh = 2MB
    const int b = bh >> 4, h = bh & 15;

    const int nt = qi + 1;
    const int lo = (quarter * nt) >> 2;
    const int hi = ((quarter + 1) * nt) >> 2;

    const bf16_t* Qb = Qc + (size_t)b * Tq * Cq + h * 64;
    const bf16_t* Kb = Kc + (size_t)bh * Tq * 64;
    const bf16_t* Vb = Vt + (size_t)bh * 64 * Tq;

    // Q fragments (B-operand for S^T); Q is pre-scaled by 0.125*log2e
    bf16x8 qf[2];
    {
        const bf16_t* qrow = Qb + (size_t)(q0 + wave * 16 + lrow) * Cq + lg * 8;
        qf[0] = *(const bf16x8*)(qrow);
        qf[1] = *(const bf16x8*)(qrow + 32);
    }

    // staging slots (swizzled): thread covers slots tid and tid+256
    const int s0 = tid, s1 = tid + 256;
    const int r0 = s0 >> 3, cg0 = (s0 & 7) ^ (r0 & 7);
    const int r1 = s1 >> 3, cg1 = (s1 & 7) ^ (r1 & 7);

    bf16x8 kr0, kr1, vr0, vr1;
    if (lo < hi) {
        const int key0 = lo * 64;
        kr0 = *(const bf16x8*)&Kb[(size_t)(key0 + r0) * 64 + cg0 * 8];
        kr1 = *(const bf16x8*)&Kb[(size_t)(key0 + r1) * 64 + cg1 * 8];
        vr0 = *(const bf16x8*)&Vb[(size_t)r0 * Tq + key0 + cg0 * 8];
        vr1 = *(const bf16x8*)&Vb[(size_t)r1 * Tq + key0 + cg1 * 8];
    }

    f32x4 oacc[4] = {};
    float n2a = 0.f, n2b = 0.f;
    int cur = 0;

    for (int kt = lo; kt < hi; kt++) {
        // write the prefetched tile into buf cur (compiler inserts vmcnt wait here)
        bf16_t* ksp = Ks[cur];
        bf16_t* vsp = Vs[cur];
        *(bf16x8*)&ksp[s0 * 8] = kr0;
        *(bf16x8*)&ksp[s1 * 8] = kr1;
        *(bf16x8*)&vsp[s0 * 8] = vr0;
        *(bf16x8*)&vsp[s1 * 8] = vr1;

        if (kt + 1 < hi) {  // issue next prefetch; in flight during compute below
            const int k1 = (kt + 1) * 64;
            kr0 = *(const bf16x8*)&Kb[(size_t)(k1 + r0) * 64 + cg0 * 8];
            kr1 = *(const bf16x8*)&Kb[(size_t)(k1 + r1) * 64 + cg1 * 8];
            vr0 = *(const bf16x8*)&Vb[(size_t)r0 * Tq + k1 + cg0 * 8];
            vr1 = *(const bf16x8*)&Vb[(size_t)r1 * Tq + k1 + cg1 * 8];
        }

        __syncthreads();  // writes of buf cur visible; single barrier per tile

        // S^T = K Q^T : C-layout gives lane 4 consecutive KEYS (rows) for one q (col)
        f32x4 sacc[4];
        #pragma unroll
        for (int j = 0; j < 4; j++) {
            int r = j * 16 + lrow;
            bf16x8 kf0 = *(const bf16x8*)&ksp[SWZ(r, lg)];
            bf16x8 kf1 = *(const bf16x8*)&ksp[SWZ(r, 4 + lg)];
            f32x4 z = {};
            z = MFMA_BF16(kf0, qf[0], z);
            sacc[j] = MFMA_BF16(kf1, qf[1], z);
        }

        // log2-domain softplus, Q pre-scaled: w = log2(1 + 2^s). |s| <~ 9, no overflow.
        // pk[j] = {pack01, pack23}: keys j*16+er+{0,1} and +{2,3} for q = wave*16+ec.
        const bool diag = (kt == qi);  // wave-uniform branch
        uint32_t pk[4][2];
        #pragma unroll
        for (int j = 0; j < 4; j++) {
            bf16x4 wb;
            #pragma unroll
            for (int v = 0; v < 4; v++) {
                float u = __builtin_amdgcn_exp2f(sacc[j][v]);
                float w = __builtin_amdgcn_logf(1.f + u);  // v_log = log2
                if (diag && (j * 16 + er + v > wave * 16 + ec)) w = 0.f;   // key > q
                if (j & 1) n2b += w * w; else n2a += w * w;
                wb[v] = (bf16_t)w;
            }
            u32x2 pw = *(u32x2*)&wb;
            pk[j][0] = pw.x; pk[j][1] = pw.y;
        }

        // O += W V, W redistributed in-register (no LDS round-trip).
        #pragma unroll
        for (int s2 = 0; s2 < 2; s2++) {
            u32x2 t0 = __builtin_amdgcn_permlane32_swap(pk[2 * s2][0], pk[2 * s2 + 1][0],
                                                        false, false);
            u32x2 w02 = __builtin_amdgcn_permlane16_swap(t0.x, t0.y, false, false);
            u32x2 t1 = __builtin_amdgcn_permlane32_swap(pk[2 * s2][1], pk[2 * s2 + 1][1],
                                                        false, false);
            u32x2 w13 = __builtin_amdgcn_permlane16_swap(t1.x, t1.y, false, false);
            u32x4 ww = {w02.x, w13.x, w02.y, w13.y};  // keys {0,1},{2,3},{4,5},{6,7} + lg*8
            bf16x8 wf = *(bf16x8*)&ww;
            #pragma unroll
            for (int jd = 0; jd < 4; jd++) {
                bf16x8 vf = *(const bf16x8*)&vsp[SWZ(jd * 16 + lrow, s2 * 4 + lg)];
                oacc[jd] = MFMA_BF16(wf, vf, oacc[jd]);
            }
        }
        cur ^= 1;
    }

    // n2 lives per lane for q = wave*16+ec; reduce over the 4 lane-groups
    float n2 = n2a + n2b;
    n2 += __shfl_xor(n2, 16, 64);
    n2 += __shfl_xor(n2, 32, 64);

    // partial epilogue (unconditional: zero-iteration blocks must write zeros over poison)
    bf16_t* Op = (quarter == 0 ? Op0 : quarter == 1 ? Op1 : quarter == 2 ? Op2 : Op3)
               + ((size_t)bh * 32 + qi) * 4096;
    #pragma unroll
    for (int jd = 0; jd < 4; jd++) {
        #pragma unroll
        for (int v = 0; v < 4; v++) {
            Op[(wave * 16 + er + v) * 64 + jd * 16 + ec] = (bf16_t)oacc[jd][v];
        }
    }
    if (lg == 0) {
        n2part[((size_t)quarter * 1024 + bh * 32 + qi) * 64 + wave * 16 + ec] = n2;
    }
}

// ---------- combine 4 partials: ao = (ΣO) * rsqrt(Σn2) ----------
__global__ __launch_bounds__(256)
void combine_kernel(const bf16_t* __restrict__ O0, const bf16_t* __restrict__ O1,
                    const bf16_t* __restrict__ O2, const bf16_t* __restrict__ O3,
                    const float* __restrict__ n2part, bf16_t* __restrict__ ao) {
    const int qi = blockIdx.x;
    const int bh = blockIdx.y;
    const int b = bh >> 4, h = bh & 15;
    const int t = threadIdx.x;
    const size_t base = ((size_t)bh * 32 + qi) * 4096;
    const float* np = n2part + ((size_t)bh * 32 + qi) * 64;
    #pragma unroll
    for (int i = 0; i < 2; i++) {
        int idx = i * 2048 + t * 8;
        int row = idx >> 6, col = idx & 63;
        bf16x8 a0 = *(const bf16x8*)(O0 + base + idx);
        bf16x8 a1 = *(const bf16x8*)(O1 + base + idx);
        bf16x8 a2 = *(const bf16x8*)(O2 + base + idx);
        bf16x8 a3 = *(const bf16x8*)(O3 + base + idx);
        float nsum = np[row] + np[(size_t)1024 * 64 + row]
                   + np[(size_t)2048 * 64 + row] + np[(size_t)3072 * 64 + row];
        float inv = rsqrtf(nsum);
        bf16x8 o;
        #pragma unroll
        for (int j = 0; j < 8; j++)
            o[j] = (bf16_t)(((float)a0[j] + (float)a1[j] + (float)a2[j] + (float)a3[j]) * inv);
        *(bf16x8*)(ao + (size_t)(b * Tq + qi * 64 + row) * Cq + h * HSq + col) = o;
    }
}

// ---------- launch ----------
extern "C" void kernel_launch(void* const* d_in, const int* in_sizes, int n_in,
                              void* d_out, int out_size, void* d_ws, size_t ws_size,
                              hipStream_t stream) {
    const float* x     = (const float*)d_in[0];
    const float* wqkv  = (const float*)d_in[1];
    const float* wproj = (const float*)d_in[2];
    const float* bproj = (const float*)d_in[3];
    float* out = (float*)d_out;

    // workspace lifetime plan (64 MB):
    //  phase1 cvt+gemm1: wprojb[0,2) xb[2,10) wqkvb[10,16) qcb[16,24) kcb[24,32) vtb[32,40)
    //  phase2 attn:      op0 over dead xb[2,10), n2 over dead wqkvb[10,11), op1[40,48)
    //                    op2[48,56) op3[56,64)
    //  phase3 combine:   ao over dead kcb[24,32)
    //  phase4 gemm2:     reads ao[24,32) + wprojb[0,2)
    char* ws = (char*)d_ws;
    bf16_t* wprojb = (bf16_t*)(ws);
    bf16_t* xb     = (bf16_t*)(ws + ( 2u << 20));
    bf16_t* wqkvb  = (bf16_t*)(ws + (10u << 20));
    bf16_t* qcb    = (bf16_t*)(ws + (16u << 20));
    bf16_t* kcb    = (bf16_t*)(ws + (24u << 20));
    bf16_t* vtb    = (bf16_t*)(ws + (32u << 20));
    bf16_t* opart0 = (bf16_t*)(ws + ( 2u << 20));
    float*  n2part = (float*)(ws + (10u << 20));
    bf16_t* opart1 = (bf16_t*)(ws + (40u << 20));
    bf16_t* opart2 = (bf16_t*)(ws + (48u << 20));
    bf16_t* opart3 = (bf16_t*)(ws + (56u << 20));
    bf16_t* aob    = (bf16_t*)(ws + (24u << 20));

    cvt_all<<<8192, 256, 0, stream>>>(x, wqkv, wproj, xb, wqkvb, wprojb);

    // QKV projection with fused layout epilogue: Qc (pre-scaled) / Kc / V^T
    // single-buffer (3 blocks/CU: implicit wave overlap already hides the drain)
    gemm_bt<128, 2, 0><<<dim3(24, 32), 256, 0, stream>>>(xb, wqkvb, nullptr, nullptr,
                                                         qcb, kcb, vtb, Mrows, 3 * Cq, Cq);
    // attention: grid transposed (bh, raw) -> XCD-local K/V + globally heavy-first
    attn_kernel<<<dim3(32, 128), 256, 0, stream>>>(qcb, kcb, vtb,
                                                   opart0, opart1, opart2, opart3, n2part);
    combine_kernel<<<dim3(32, 32), 256, 0, stream>>>(opart0, opart1, opart2, opart3,
                                                     n2part, aob);
    // output projection + bias: BM=128 + 2-phase dbuf pipeline (R13). Grid 256 =
    // 1 block/CU is now fine: loads fly during compute, one barrier per K-step.
    gemm_bt<128, 1, 1><<<dim3(8, 32), 256, 0, stream>>>(aob, wprojb, (void*)out, bproj,
                                                        nullptr, nullptr, nullptr, Mrows, Cq, Cq);
}

// Round 7
// 172.891 us; speedup vs baseline: 1.0414x; 1.0414x over previous
//
#include <hip/hip_runtime.h>
#include <cstdint>
#include <cstddef>

// ---------- types ----------
typedef __bf16 bf16_t;
typedef __bf16 bf16x8 __attribute__((ext_vector_type(8)));
typedef __bf16 bf16x4 __attribute__((ext_vector_type(4)));
typedef float  f32x4  __attribute__((ext_vector_type(4)));
typedef unsigned int u32x2 __attribute__((ext_vector_type(2)));
typedef unsigned int u32x4 __attribute__((ext_vector_type(4)));

#define MFMA_BF16(a, b, c) __builtin_amdgcn_mfma_f32_16x16x32_bf16((a), (b), (c), 0, 0, 0)

// async global->LDS, 16B per lane. LDS dest must be wave-uniform base + lane*16.
__device__ __forceinline__ void async_load16(const void* g, void* l) {
    __builtin_amdgcn_global_load_lds((const __attribute__((address_space(1))) void*)g,
                                     (__attribute__((address_space(3))) void*)l,
                                     16, 0, 0);
}

// XOR-swizzled LDS layout for tiles with 8 16B-chunks per row (64 bf16/row).
// chunk (r, cg) lives at slot r*8 + (cg ^ (r&7)); returns bf16 element offset.
#define SWZ(r, cg) ((((r) << 3) | ((cg) ^ ((r) & 7))) << 3)

// ---------- problem constants ----------
#define Bq   2
#define Tq   2048
#define Cq   1024
#define Hq   16
#define HSq  64
#define Mrows 4096   // B*T

// softplus scale folded into Q at the gemm1 epilogue: 0.125 * log2(e)
#define QSCALE 0.18033688f

// ---------- fused fp32 -> bf16 convert for x, W_qkv, W_proj ----------
__global__ __launch_bounds__(256)
void cvt_all(const float* __restrict__ x, const float* __restrict__ wqkv,
             const float* __restrict__ wproj,
             bf16_t* __restrict__ xb, bf16_t* __restrict__ wqkvb,
             bf16_t* __restrict__ wprojb) {
    size_t gid = (size_t)blockIdx.x * 256 + threadIdx.x;  // quad index
    const float* src; bf16_t* dst; size_t off;
    if (gid < 1048576)      { src = x;     dst = xb;     off = gid; }
    else if (gid < 1835008) { src = wqkv;  dst = wqkvb;  off = gid - 1048576; }
    else                    { src = wproj; dst = wprojb; off = gid - 1835008; }
    float4 v = ((const float4*)src)[off];
    bf16x4 o;
    o[0] = (bf16_t)v.x; o[1] = (bf16_t)v.y; o[2] = (bf16_t)v.z; o[3] = (bf16_t)v.w;
    *(bf16x4*)(dst + off * 4) = o;
}

// ---------- GEMM: C[m][n] = sum_k A[m][k]*B[n][k], A:[M,K], B:[N,K] row-major ----------
// BK=64, XOR-swizzled LDS. EPI=1: fp32 out + bias. EPI=2: QKV split epilogue.
// R10/R13 post-mortems: keep >= 2 co-resident blocks/CU. Both the BM=128 2-barrier
// (R2) and the BM=128 2-phase dbuf pipeline (R6) at 1 block/CU lost ~3-5us vs
// BM=64 x 2 blocks/CU: gemm2's A operand is freshly-written (HBM-latency ~900cy),
// so single-deep intra-block prefetch cannot cover it; cross-block overlap can.
template <int BM, int EPI>
__global__ __launch_bounds__(256)
void gemm_bt(const bf16_t* __restrict__ A, const bf16_t* __restrict__ B,
             void* __restrict__ Cout, const float* __restrict__ bias,
             bf16_t* __restrict__ qc, bf16_t* __restrict__ kc, bf16_t* __restrict__ vtp,
             int M, int N, int K) {
    constexpr int MR = BM / 32;        // MFMA row-tiles per wave
    constexpr int ACH = BM * 8 / 256;  // A-chunks per thread (BM=128 -> 4, 64 -> 2)
    __shared__ __align__(16) bf16_t As[BM * 64];
    __shared__ __align__(16) bf16_t Bs[128 * 64];

    const int tid  = threadIdx.x;
    const int wave = tid >> 6;
    const int lane = tid & 63;
    const int m0 = blockIdx.y * BM;
    const int n0 = blockIdx.x * 128;
    const int wm = (wave >> 1) * (BM / 2);
    const int wn = (wave & 1) * 64;
    const int lrow = lane & 15;
    const int lg   = lane >> 4;

    f32x4 acc[MR][4] = {};

    const bf16_t* Ag = A + (size_t)m0 * K;
    const bf16_t* Bg = B + (size_t)n0 * K;

    for (int k0 = 0; k0 < K; k0 += 64) {
        #pragma unroll
        for (int i = 0; i < ACH; i++) {
            int s = i * 256 + tid;
            int r = s >> 3, cg = (s & 7) ^ (r & 7);
            async_load16(Ag + (size_t)r * K + k0 + cg * 8, &As[s * 8]);
        }
        #pragma unroll
        for (int i = 0; i < 4; i++) {
            int s = i * 256 + tid;
            int r = s >> 3, cg = (s & 7) ^ (r & 7);
            async_load16(Bg + (size_t)r * K + k0 + cg * 8, &Bs[s * 8]);
        }
        __syncthreads();

        #pragma unroll
        for (int kk = 0; kk < 2; kk++) {
            bf16x8 af[MR], bfr[4];
            #pragma unroll
            for (int r = 0; r < MR; r++)
                af[r] = *(const bf16x8*)&As[SWZ(wm + r * 16 + lrow, kk * 4 + lg)];
            #pragma unroll
            for (int c = 0; c < 4; c++)
                bfr[c] = *(const bf16x8*)&Bs[SWZ(wn + c * 16 + lrow, kk * 4 + lg)];
            #pragma unroll
            for (int r = 0; r < MR; r++)
                #pragma unroll
                for (int c = 0; c < 4; c++)
                    acc[r][c] = MFMA_BF16(af[r], bfr[c], acc[r][c]);
        }
        __syncthreads();
    }

    const int er = (lane >> 4) * 4;
    const int ec = lane & 15;
    #pragma unroll
    for (int r = 0; r < MR; r++) {
        #pragma unroll
        for (int c = 0; c < 4; c++) {
            int m = m0 + wm + r * 16 + er;
            int n = n0 + wn + c * 16 + ec;
            if (EPI == 1) {
                #pragma unroll
                for (int v = 0; v < 4; v++)
                    ((float*)Cout)[(size_t)(m + v) * N + n] = acc[r][c][v] + bias[n];
            } else {
                int bb = m >> 11, t = m & 2047;   // block-uniform region (n0 128-aligned)
                if (n < 1024) {
                    // pre-scale Q so attn's S == t directly (log2-domain softplus)
                    #pragma unroll
                    for (int v = 0; v < 4; v++)
                        qc[(size_t)(m + v) * 1024 + n] = (bf16_t)(acc[r][c][v] * QSCALE);
                } else if (n < 2048) {
                    int h = (n - 1024) >> 6, d = (n - 1024) & 63;
                    bf16_t* p = kc + ((size_t)(bb * 16 + h) * Tq + t) * 64 + d;
                    #pragma unroll
                    for (int v = 0; v < 4; v++) p[v * 64] = (bf16_t)acc[r][c][v];
                } else {
                    int h = (n - 2048) >> 6, d = (n - 2048) & 63;
                    bf16x4 o;
                    #pragma unroll
                    for (int v = 0; v < 4; v++) o[v] = (bf16_t)acc[r][c][v];
                    *(bf16x4*)&vtp[((size_t)(bb * 16 + h) * 64 + d) * Tq + t] = o;
                }
            }
        }
    }
}

// ---------- attention: R6 dataflow, k-split 2 (R14; was 4) ----------
// R8: grid transposed (bh, raw) -> XCD = bh%8 owns 4 bh = 2MB K/V (L2-resident);
//     softplus in log2 domain with Q pre-scaled.
// R9..R12: dbuf single-barrier + permlane W redistribution (all ~neutral; kept).
// R14: k-split 4 -> 2. Halves partial-O traffic (32->16MB), Q-tile re-reads
//     (32->16MB), per-block fixed costs (4096->2048 blocks), and combine input
//     (40->24MB). Heaviest blocks (16 tiles) dispatch first (heavy-first order).
__global__ __launch_bounds__(256)
void attn_kernel(const bf16_t* __restrict__ Qc, const bf16_t* __restrict__ Kc,
                 const bf16_t* __restrict__ Vt,
                 bf16_t* __restrict__ Op0, bf16_t* __restrict__ Op1,
                 float* __restrict__ n2part) {
    __shared__ __align__(16) bf16_t Ks[2][64 * 64];  // swizzled [key][d], double-buffered
    __shared__ __align__(16) bf16_t Vs[2][64 * 64];  // swizzled [d][key], double-buffered

    const int tid = threadIdx.x;
    const int wave = tid >> 6;
    const int lane = tid & 63;
    const int lrow = lane & 15;
    const int lg   = lane >> 4;     // 0..3
    const int er = lg * 4;
    const int ec = lane & 15;

    const int raw  = blockIdx.y;          // 0..63, globally heavy-first
    const int qi   = 31 - (raw >> 1);
    const int half = raw & 1;
    const int q0   = qi * 64;
    const int bh = blockIdx.x;            // XCD = bh % 8 -> per-XCD K/V = 4 bh = 2MB
    const int b = bh >> 4, h = bh & 15;

    const int nt = qi + 1;
    const int lo = (half * nt) >> 1;
    const int hi = ((half + 1) * nt) >> 1;

    const bf16_t* Qb = Qc + (size_t)b * Tq * Cq + h * 64;
    const bf16_t* Kb = Kc + (size_t)bh * Tq * 64;
    const bf16_t* Vb = Vt + (size_t)bh * 64 * Tq;

    // Q fragments (B-operand for S^T); Q is pre-scaled by 0.125*log2e
    bf16x8 qf[2];
    {
        const bf16_t* qrow = Qb + (size_t)(q0 + wave * 16 + lrow) * Cq + lg * 8;
        qf[0] = *(const bf16x8*)(qrow);
        qf[1] = *(const bf16x8*)(qrow + 32);
    }

    // staging slots (swizzled): thread covers slots tid and tid+256
    const int s0 = tid, s1 = tid + 256;
    const int r0 = s0 >> 3, cg0 = (s0 & 7) ^ (r0 & 7);
    const int r1 = s1 >> 3, cg1 = (s1 & 7) ^ (r1 & 7);

    bf16x8 kr0, kr1, vr0, vr1;
    if (lo < hi) {
        const int key0 = lo * 64;
        kr0 = *(const bf16x8*)&Kb[(size_t)(key0 + r0) * 64 + cg0 * 8];
        kr1 = *(const bf16x8*)&Kb[(size_t)(key0 + r1) * 64 + cg1 * 8];
        vr0 = *(const bf16x8*)&Vb[(size_t)r0 * Tq + key0 + cg0 * 8];
        vr1 = *(const bf16x8*)&Vb[(size_t)r1 * Tq + key0 + cg1 * 8];
    }

    f32x4 oacc[4] = {};
    float n2a = 0.f, n2b = 0.f;
    int cur = 0;

    for (int kt = lo; kt < hi; kt++) {
        // write the prefetched tile into buf cur (compiler inserts vmcnt wait here)
        bf16_t* ksp = Ks[cur];
        bf16_t* vsp = Vs[cur];
        *(bf16x8*)&ksp[s0 * 8] = kr0;
        *(bf16x8*)&ksp[s1 * 8] = kr1;
        *(bf16x8*)&vsp[s0 * 8] = vr0;
        *(bf16x8*)&vsp[s1 * 8] = vr1;

        if (kt + 1 < hi) {  // issue next prefetch; in flight during compute below
            const int k1 = (kt + 1) * 64;
            kr0 = *(const bf16x8*)&Kb[(size_t)(k1 + r0) * 64 + cg0 * 8];
            kr1 = *(const bf16x8*)&Kb[(size_t)(k1 + r1) * 64 + cg1 * 8];
            vr0 = *(const bf16x8*)&Vb[(size_t)r0 * Tq + k1 + cg0 * 8];
            vr1 = *(const bf16x8*)&Vb[(size_t)r1 * Tq + k1 + cg1 * 8];
        }

        __syncthreads();  // writes of buf cur visible; single barrier per tile

        // S^T = K Q^T : C-layout gives lane 4 consecutive KEYS (rows) for one q (col)
        f32x4 sacc[4];
        #pragma unroll
        for (int j = 0; j < 4; j++) {
            int r = j * 16 + lrow;
            bf16x8 kf0 = *(const bf16x8*)&ksp[SWZ(r, lg)];
            bf16x8 kf1 = *(const bf16x8*)&ksp[SWZ(r, 4 + lg)];
            f32x4 z = {};
            z = MFMA_BF16(kf0, qf[0], z);
            sacc[j] = MFMA_BF16(kf1, qf[1], z);
        }

        // log2-domain softplus, Q pre-scaled: w = log2(1 + 2^s). |s| <~ 9, no overflow.
        // pk[j] = {pack01, pack23}: keys j*16+er+{0,1} and +{2,3} for q = wave*16+ec.
        const bool diag = (kt == qi);  // wave-uniform branch
        uint32_t pk[4][2];
        #pragma unroll
        for (int j = 0; j < 4; j++) {
            bf16x4 wb;
            #pragma unroll
            for (int v = 0; v < 4; v++) {
                float u = __builtin_amdgcn_exp2f(sacc[j][v]);
                float w = __builtin_amdgcn_logf(1.f + u);  // v_log = log2
                if (diag && (j * 16 + er + v > wave * 16 + ec)) w = 0.f;   // key > q
                if (j & 1) n2b += w * w; else n2a += w * w;
                wb[v] = (bf16_t)w;
            }
            u32x2 pw = *(u32x2*)&wb;
            pk[j][0] = pw.x; pk[j][1] = pw.y;
        }

        // O += W V, W redistributed in-register (no LDS round-trip).
        #pragma unroll
        for (int s2 = 0; s2 < 2; s2++) {
            u32x2 t0 = __builtin_amdgcn_permlane32_swap(pk[2 * s2][0], pk[2 * s2 + 1][0],
                                                        false, false);
            u32x2 w02 = __builtin_amdgcn_permlane16_swap(t0.x, t0.y, false, false);
            u32x2 t1 = __builtin_amdgcn_permlane32_swap(pk[2 * s2][1], pk[2 * s2 + 1][1],
                                                        false, false);
            u32x2 w13 = __builtin_amdgcn_permlane16_swap(t1.x, t1.y, false, false);
            u32x4 ww = {w02.x, w13.x, w02.y, w13.y};  // keys {0,1},{2,3},{4,5},{6,7} + lg*8
            bf16x8 wf = *(bf16x8*)&ww;
            #pragma unroll
            for (int jd = 0; jd < 4; jd++) {
                bf16x8 vf = *(const bf16x8*)&vsp[SWZ(jd * 16 + lrow, s2 * 4 + lg)];
                oacc[jd] = MFMA_BF16(wf, vf, oacc[jd]);
            }
        }
        cur ^= 1;
    }

    // n2 lives per lane for q = wave*16+ec; reduce over the 4 lane-groups
    float n2 = n2a + n2b;
    n2 += __shfl_xor(n2, 16, 64);
    n2 += __shfl_xor(n2, 32, 64);

    // partial epilogue (unconditional: zero-iteration blocks must write zeros over poison)
    bf16_t* Op = (half == 0 ? Op0 : Op1) + ((size_t)bh * 32 + qi) * 4096;
    #pragma unroll
    for (int jd = 0; jd < 4; jd++) {
        #pragma unroll
        for (int v = 0; v < 4; v++) {
            Op[(wave * 16 + er + v) * 64 + jd * 16 + ec] = (bf16_t)oacc[jd][v];
        }
    }
    if (lg == 0) {
        n2part[((size_t)half * 1024 + bh * 32 + qi) * 64 + wave * 16 + ec] = n2;
    }
}

// ---------- combine 2 partials: ao = (ΣO) * rsqrt(Σn2) ----------
__global__ __launch_bounds__(256)
void combine_kernel(const bf16_t* __restrict__ O0, const bf16_t* __restrict__ O1,
                    const float* __restrict__ n2part, bf16_t* __restrict__ ao) {
    const int qi = blockIdx.x;
    const int bh = blockIdx.y;
    const int b = bh >> 4, h = bh & 15;
    const int t = threadIdx.x;
    const size_t base = ((size_t)bh * 32 + qi) * 4096;
    const float* np = n2part + ((size_t)bh * 32 + qi) * 64;
    #pragma unroll
    for (int i = 0; i < 2; i++) {
        int idx = i * 2048 + t * 8;
        int row = idx >> 6, col = idx & 63;
        bf16x8 a0 = *(const bf16x8*)(O0 + base + idx);
        bf16x8 a1 = *(const bf16x8*)(O1 + base + idx);
        float nsum = np[row] + np[(size_t)1024 * 64 + row];
        float inv = rsqrtf(nsum);
        bf16x8 o;
        #pragma unroll
        for (int j = 0; j < 8; j++)
            o[j] = (bf16_t)(((float)a0[j] + (float)a1[j]) * inv);
        *(bf16x8*)(ao + (size_t)(b * Tq + qi * 64 + row) * Cq + h * HSq + col) = o;
    }
}

// ---------- launch ----------
extern "C" void kernel_launch(void* const* d_in, const int* in_sizes, int n_in,
                              void* d_out, int out_size, void* d_ws, size_t ws_size,
                              hipStream_t stream) {
    const float* x     = (const float*)d_in[0];
    const float* wqkv  = (const float*)d_in[1];
    const float* wproj = (const float*)d_in[2];
    const float* bproj = (const float*)d_in[3];
    float* out = (float*)d_out;

    // workspace lifetime plan (64 MB):
    //  phase1 cvt+gemm1: wprojb[0,2) xb[2,10) wqkvb[10,16) qcb[16,24) kcb[24,32) vtb[32,40)
    //  phase2 attn:      op0 over dead xb[2,10), n2 over dead wqkvb[10,11), op1[40,48)
    //  phase3 combine:   ao over dead kcb[24,32)
    //  phase4 gemm2:     reads ao[24,32) + wprojb[0,2)
    char* ws = (char*)d_ws;
    bf16_t* wprojb = (bf16_t*)(ws);
    bf16_t* xb     = (bf16_t*)(ws + ( 2u << 20));
    bf16_t* wqkvb  = (bf16_t*)(ws + (10u << 20));
    bf16_t* qcb    = (bf16_t*)(ws + (16u << 20));
    bf16_t* kcb    = (bf16_t*)(ws + (24u << 20));
    bf16_t* vtb    = (bf16_t*)(ws + (32u << 20));
    bf16_t* opart0 = (bf16_t*)(ws + ( 2u << 20));
    float*  n2part = (float*)(ws + (10u << 20));
    bf16_t* opart1 = (bf16_t*)(ws + (40u << 20));
    bf16_t* aob    = (bf16_t*)(ws + (24u << 20));

    cvt_all<<<8192, 256, 0, stream>>>(x, wqkv, wproj, xb, wqkvb, wprojb);

    // QKV projection with fused layout epilogue: Qc (pre-scaled) / Kc / V^T
    gemm_bt<128, 2><<<dim3(24, 32), 256, 0, stream>>>(xb, wqkvb, nullptr, nullptr,
                                                      qcb, kcb, vtb, Mrows, 3 * Cq, Cq);
    // attention: k-split 2 (R14), grid (bh, raw) -> XCD-local K/V, heavy-first
    attn_kernel<<<dim3(32, 64), 256, 0, stream>>>(qcb, kcb, vtb,
                                                  opart0, opart1, n2part);
    combine_kernel<<<dim3(32, 32), 256, 0, stream>>>(opart0, opart1, n2part, aob);
    // output projection + bias: BM=64, grid 8x64 = 512 blocks = 2/CU (best measured)
    gemm_bt<64, 1><<<dim3(8, 64), 256, 0, stream>>>(aob, wprojb, (void*)out, bproj,
                                                    nullptr, nullptr, nullptr, Mrows, Cq, Cq);
}

// Round 8
// 167.834 us; speedup vs baseline: 1.0728x; 1.0301x over previous
//
#include <hip/hip_runtime.h>
#include <cstdint>
#include <cstddef>

// ---------- types ----------
typedef __bf16 bf16_t;
typedef __bf16 bf16x8 __attribute__((ext_vector_type(8)));
typedef __bf16 bf16x4 __attribute__((ext_vector_type(4)));
typedef float  f32x4  __attribute__((ext_vector_type(4)));
typedef unsigned int u32x2 __attribute__((ext_vector_type(2)));
typedef unsigned int u32x4 __attribute__((ext_vector_type(4)));

#define MFMA_BF16(a, b, c) __builtin_amdgcn_mfma_f32_16x16x32_bf16((a), (b), (c), 0, 0, 0)

// async global->LDS, 16B per lane. LDS dest must be wave-uniform base + lane*16.
__device__ __forceinline__ void async_load16(const void* g, void* l) {
    __builtin_amdgcn_global_load_lds((const __attribute__((address_space(1))) void*)g,
                                     (__attribute__((address_space(3))) void*)l,
                                     16, 0, 0);
}

// XOR-swizzled LDS layout for tiles with 8 16B-chunks per row (64 bf16/row).
// chunk (r, cg) lives at slot r*8 + (cg ^ (r&7)); returns bf16 element offset.
#define SWZ(r, cg) ((((r) << 3) | ((cg) ^ ((r) & 7))) << 3)

// ---------- problem constants ----------
#define Bq   2
#define Tq   2048
#define Cq   1024
#define Hq   16
#define HSq  64
#define Mrows 4096   // B*T

// softplus scale folded into Q at the gemm1 epilogue: 0.125 * log2(e)
#define QSCALE 0.18033688f

// ---------- fused fp32 -> bf16 convert for x, W_qkv, W_proj ----------
__global__ __launch_bounds__(256)
void cvt_all(const float* __restrict__ x, const float* __restrict__ wqkv,
             const float* __restrict__ wproj,
             bf16_t* __restrict__ xb, bf16_t* __restrict__ wqkvb,
             bf16_t* __restrict__ wprojb) {
    size_t gid = (size_t)blockIdx.x * 256 + threadIdx.x;  // quad index
    const float* src; bf16_t* dst; size_t off;
    if (gid < 1048576)      { src = x;     dst = xb;     off = gid; }
    else if (gid < 1835008) { src = wqkv;  dst = wqkvb;  off = gid - 1048576; }
    else                    { src = wproj; dst = wprojb; off = gid - 1835008; }
    float4 v = ((const float4*)src)[off];
    bf16x4 o;
    o[0] = (bf16_t)v.x; o[1] = (bf16_t)v.y; o[2] = (bf16_t)v.z; o[3] = (bf16_t)v.w;
    *(bf16x4*)(dst + off * 4) = o;
}

// ---------- GEMM: C[m][n] = sum_k A[m][k]*B[n][k], A:[M,K], B:[N,K] row-major ----------
// BK=64, XOR-swizzled LDS. EPI=1: fp32 out + bias. EPI=2: QKV split epilogue.
// R10/R13 post-mortems: keep >= 2 co-resident blocks/CU. Both the BM=128 2-barrier
// (R2) and the BM=128 2-phase dbuf pipeline (R6) at 1 block/CU lost ~3-5us vs
// BM=64 x 2 blocks/CU: gemm2's A operand is freshly-written (HBM-latency ~900cy),
// so single-deep intra-block prefetch cannot cover it; cross-block overlap can.
template <int BM, int EPI>
__global__ __launch_bounds__(256)
void gemm_bt(const bf16_t* __restrict__ A, const bf16_t* __restrict__ B,
             void* __restrict__ Cout, const float* __restrict__ bias,
             bf16_t* __restrict__ qc, bf16_t* __restrict__ kc, bf16_t* __restrict__ vtp,
             int M, int N, int K) {
    constexpr int MR = BM / 32;        // MFMA row-tiles per wave
    constexpr int ACH = BM * 8 / 256;  // A-chunks per thread (BM=128 -> 4, 64 -> 2)
    __shared__ __align__(16) bf16_t As[BM * 64];
    __shared__ __align__(16) bf16_t Bs[128 * 64];

    const int tid  = threadIdx.x;
    const int wave = tid >> 6;
    const int lane = tid & 63;
    const int m0 = blockIdx.y * BM;
    const int n0 = blockIdx.x * 128;
    const int wm = (wave >> 1) * (BM / 2);
    const int wn = (wave & 1) * 64;
    const int lrow = lane & 15;
    const int lg   = lane >> 4;

    f32x4 acc[MR][4] = {};

    const bf16_t* Ag = A + (size_t)m0 * K;
    const bf16_t* Bg = B + (size_t)n0 * K;

    for (int k0 = 0; k0 < K; k0 += 64) {
        #pragma unroll
        for (int i = 0; i < ACH; i++) {
            int s = i * 256 + tid;
            int r = s >> 3, cg = (s & 7) ^ (r & 7);
            async_load16(Ag + (size_t)r * K + k0 + cg * 8, &As[s * 8]);
        }
        #pragma unroll
        for (int i = 0; i < 4; i++) {
            int s = i * 256 + tid;
            int r = s >> 3, cg = (s & 7) ^ (r & 7);
            async_load16(Bg + (size_t)r * K + k0 + cg * 8, &Bs[s * 8]);
        }
        __syncthreads();

        #pragma unroll
        for (int kk = 0; kk < 2; kk++) {
            bf16x8 af[MR], bfr[4];
            #pragma unroll
            for (int r = 0; r < MR; r++)
                af[r] = *(const bf16x8*)&As[SWZ(wm + r * 16 + lrow, kk * 4 + lg)];
            #pragma unroll
            for (int c = 0; c < 4; c++)
                bfr[c] = *(const bf16x8*)&Bs[SWZ(wn + c * 16 + lrow, kk * 4 + lg)];
            #pragma unroll
            for (int r = 0; r < MR; r++)
                #pragma unroll
                for (int c = 0; c < 4; c++)
                    acc[r][c] = MFMA_BF16(af[r], bfr[c], acc[r][c]);
        }
        __syncthreads();
    }

    const int er = (lane >> 4) * 4;
    const int ec = lane & 15;
    #pragma unroll
    for (int r = 0; r < MR; r++) {
        #pragma unroll
        for (int c = 0; c < 4; c++) {
            int m = m0 + wm + r * 16 + er;
            int n = n0 + wn + c * 16 + ec;
            if (EPI == 1) {
                #pragma unroll
                for (int v = 0; v < 4; v++)
                    ((float*)Cout)[(size_t)(m + v) * N + n] = acc[r][c][v] + bias[n];
            } else {
                int bb = m >> 11, t = m & 2047;   // block-uniform region (n0 128-aligned)
                if (n < 1024) {
                    // pre-scale Q so attn's S == t directly (log2-domain softplus)
                    #pragma unroll
                    for (int v = 0; v < 4; v++)
                        qc[(size_t)(m + v) * 1024 + n] = (bf16_t)(acc[r][c][v] * QSCALE);
                } else if (n < 2048) {
                    int h = (n - 1024) >> 6, d = (n - 1024) & 63;
                    bf16_t* p = kc + ((size_t)(bb * 16 + h) * Tq + t) * 64 + d;
                    #pragma unroll
                    for (int v = 0; v < 4; v++) p[v * 64] = (bf16_t)acc[r][c][v];
                } else {
                    int h = (n - 2048) >> 6, d = (n - 2048) & 63;
                    bf16x4 o;
                    #pragma unroll
                    for (int v = 0; v < 4; v++) o[v] = (bf16_t)acc[r][c][v];
                    *(bf16x4*)&vtp[((size_t)(bb * 16 + h) * 64 + d) * Tq + t] = o;
                }
            }
        }
    }
}

// ---------- attention: R6 dataflow, k-split 1 (R15; R14 was 2, R6 was 4) ----------
// R8: grid (bh, qi) -> XCD = bh%8 owns 4 bh = 2MB K/V (L2-resident); log2-softplus.
// R9..R12: dbuf single-barrier + permlane W redistribution (neutral; kept).
// R14 confirmed the traffic model (-4..7us); R15 takes it to the limit: one block
// owns a full q-row -> full n2 in-block -> normalized output written DIRECTLY
// (no partials, no combine kernel: saves 16MB partial wr + 24MB combine rd/wr +
// a dispatch). 1024 blocks = 4/CU; heavy-first (qi=31 first) kills the tail.
__global__ __launch_bounds__(256)
void attn_kernel(const bf16_t* __restrict__ Qc, const bf16_t* __restrict__ Kc,
                 const bf16_t* __restrict__ Vt, bf16_t* __restrict__ ao) {
    __shared__ __align__(16) bf16_t Ks[2][64 * 64];  // swizzled [key][d], double-buffered
    __shared__ __align__(16) bf16_t Vs[2][64 * 64];  // swizzled [d][key], double-buffered

    const int tid = threadIdx.x;
    const int wave = tid >> 6;
    const int lane = tid & 63;
    const int lrow = lane & 15;
    const int lg   = lane >> 4;     // 0..3
    const int er = lg * 4;
    const int ec = lane & 15;

    const int qi = 31 - blockIdx.y;       // heavy-first
    const int q0 = qi * 64;
    const int bh = blockIdx.x;            // XCD = bh % 8 -> per-XCD K/V = 4 bh = 2MB
    const int b = bh >> 4, h = bh & 15;

    const int hi = qi + 1;                // tiles 0..qi inclusive

    const bf16_t* Qb = Qc + (size_t)b * Tq * Cq + h * 64;
    const bf16_t* Kb = Kc + (size_t)bh * Tq * 64;
    const bf16_t* Vb = Vt + (size_t)bh * 64 * Tq;

    // Q fragments (B-operand for S^T); Q is pre-scaled by 0.125*log2e
    bf16x8 qf[2];
    {
        const bf16_t* qrow = Qb + (size_t)(q0 + wave * 16 + lrow) * Cq + lg * 8;
        qf[0] = *(const bf16x8*)(qrow);
        qf[1] = *(const bf16x8*)(qrow + 32);
    }

    // staging slots (swizzled): thread covers slots tid and tid+256
    const int s0 = tid, s1 = tid + 256;
    const int r0 = s0 >> 3, cg0 = (s0 & 7) ^ (r0 & 7);
    const int r1 = s1 >> 3, cg1 = (s1 & 7) ^ (r1 & 7);

    bf16x8 kr0, kr1, vr0, vr1;
    {
        kr0 = *(const bf16x8*)&Kb[(size_t)r0 * 64 + cg0 * 8];
        kr1 = *(const bf16x8*)&Kb[(size_t)r1 * 64 + cg1 * 8];
        vr0 = *(const bf16x8*)&Vb[(size_t)r0 * Tq + cg0 * 8];
        vr1 = *(const bf16x8*)&Vb[(size_t)r1 * Tq + cg1 * 8];
    }

    f32x4 oacc[4] = {};
    float n2a = 0.f, n2b = 0.f;
    int cur = 0;

    for (int kt = 0; kt < hi; kt++) {
        // write the prefetched tile into buf cur (compiler inserts vmcnt wait here)
        bf16_t* ksp = Ks[cur];
        bf16_t* vsp = Vs[cur];
        *(bf16x8*)&ksp[s0 * 8] = kr0;
        *(bf16x8*)&ksp[s1 * 8] = kr1;
        *(bf16x8*)&vsp[s0 * 8] = vr0;
        *(bf16x8*)&vsp[s1 * 8] = vr1;

        if (kt + 1 < hi) {  // issue next prefetch; in flight during compute below
            const int k1 = (kt + 1) * 64;
            kr0 = *(const bf16x8*)&Kb[(size_t)(k1 + r0) * 64 + cg0 * 8];
            kr1 = *(const bf16x8*)&Kb[(size_t)(k1 + r1) * 64 + cg1 * 8];
            vr0 = *(const bf16x8*)&Vb[(size_t)r0 * Tq + k1 + cg0 * 8];
            vr1 = *(const bf16x8*)&Vb[(size_t)r1 * Tq + k1 + cg1 * 8];
        }

        __syncthreads();  // writes of buf cur visible; single barrier per tile

        // S^T = K Q^T : C-layout gives lane 4 consecutive KEYS (rows) for one q (col)
        f32x4 sacc[4];
        #pragma unroll
        for (int j = 0; j < 4; j++) {
            int r = j * 16 + lrow;
            bf16x8 kf0 = *(const bf16x8*)&ksp[SWZ(r, lg)];
            bf16x8 kf1 = *(const bf16x8*)&ksp[SWZ(r, 4 + lg)];
            f32x4 z = {};
            z = MFMA_BF16(kf0, qf[0], z);
            sacc[j] = MFMA_BF16(kf1, qf[1], z);
        }

        // log2-domain softplus, Q pre-scaled: w = log2(1 + 2^s). |s| <~ 9, no overflow.
        // pk[j] = {pack01, pack23}: keys j*16+er+{0,1} and +{2,3} for q = wave*16+ec.
        const bool diag = (kt == qi);  // wave-uniform branch
        uint32_t pk[4][2];
        #pragma unroll
        for (int j = 0; j < 4; j++) {
            bf16x4 wb;
            #pragma unroll
            for (int v = 0; v < 4; v++) {
                float u = __builtin_amdgcn_exp2f(sacc[j][v]);
                float w = __builtin_amdgcn_logf(1.f + u);  // v_log = log2
                if (diag && (j * 16 + er + v > wave * 16 + ec)) w = 0.f;   // key > q
                if (j & 1) n2b += w * w; else n2a += w * w;
                wb[v] = (bf16_t)w;
            }
            u32x2 pw = *(u32x2*)&wb;
            pk[j][0] = pw.x; pk[j][1] = pw.y;
        }

        // O += W V, W redistributed in-register (no LDS round-trip).
        #pragma unroll
        for (int s2 = 0; s2 < 2; s2++) {
            u32x2 t0 = __builtin_amdgcn_permlane32_swap(pk[2 * s2][0], pk[2 * s2 + 1][0],
                                                        false, false);
            u32x2 w02 = __builtin_amdgcn_permlane16_swap(t0.x, t0.y, false, false);
            u32x2 t1 = __builtin_amdgcn_permlane32_swap(pk[2 * s2][1], pk[2 * s2 + 1][1],
                                                        false, false);
            u32x2 w13 = __builtin_amdgcn_permlane16_swap(t1.x, t1.y, false, false);
            u32x4 ww = {w02.x, w13.x, w02.y, w13.y};  // keys {0,1},{2,3},{4,5},{6,7} + lg*8
            bf16x8 wf = *(bf16x8*)&ww;
            #pragma unroll
            for (int jd = 0; jd < 4; jd++) {
                bf16x8 vf = *(const bf16x8*)&vsp[SWZ(jd * 16 + lrow, s2 * 4 + lg)];
                oacc[jd] = MFMA_BF16(wf, vf, oacc[jd]);
            }
        }
        cur ^= 1;
    }

    // n2 per lane covers q = wave*16+ec; reduce over the 4 lane-groups -> lg-uniform
    float n2 = n2a + n2b;
    n2 += __shfl_xor(n2, 16, 64);
    n2 += __shfl_xor(n2, 32, 64);

    // normalized output, written directly to attention-out [B,T,C] (no partials).
    // lane writes rows wave*16+er+v; its n2 is for q=wave*16+ec -> gather the row's
    // norm via shfl width16 from the lane with ec == er+v (n2 is lg-uniform).
    bf16_t* aop = ao + ((size_t)(b * Tq + q0 + wave * 16) * Cq) + h * HSq;
    #pragma unroll
    for (int v = 0; v < 4; v++) {
        float inv = rsqrtf(__shfl(n2, er + v, 16));
        #pragma unroll
        for (int jd = 0; jd < 4; jd++) {
            aop[(size_t)(er + v) * Cq + jd * 16 + ec] = (bf16_t)(oacc[jd][v] * inv);
        }
    }
}

// ---------- launch ----------
extern "C" void kernel_launch(void* const* d_in, const int* in_sizes, int n_in,
                              void* d_out, int out_size, void* d_ws, size_t ws_size,
                              hipStream_t stream) {
    const float* x     = (const float*)d_in[0];
    const float* wqkv  = (const float*)d_in[1];
    const float* wproj = (const float*)d_in[2];
    const float* bproj = (const float*)d_in[3];
    float* out = (float*)d_out;

    // workspace lifetime plan (64 MB):
    //  phase1 cvt+gemm1: wprojb[0,2) xb[2,10) wqkvb[10,16) qcb[16,24) kcb[24,32) vtb[32,40)
    //  phase2 attn:      reads qcb/kcb/vtb, writes ao over dead xb[2,10)
    //  phase3 gemm2:     reads ao[2,10) + wprojb[0,2)
    char* ws = (char*)d_ws;
    bf16_t* wprojb = (bf16_t*)(ws);
    bf16_t* xb     = (bf16_t*)(ws + ( 2u << 20));
    bf16_t* wqkvb  = (bf16_t*)(ws + (10u << 20));
    bf16_t* qcb    = (bf16_t*)(ws + (16u << 20));
    bf16_t* kcb    = (bf16_t*)(ws + (24u << 20));
    bf16_t* vtb    = (bf16_t*)(ws + (32u << 20));
    bf16_t* aob    = (bf16_t*)(ws + ( 2u << 20));  // over dead xb

    cvt_all<<<8192, 256, 0, stream>>>(x, wqkv, wproj, xb, wqkvb, wprojb);

    // QKV projection with fused layout epilogue: Qc (pre-scaled) / Kc / V^T
    gemm_bt<128, 2><<<dim3(24, 32), 256, 0, stream>>>(xb, wqkvb, nullptr, nullptr,
                                                      qcb, kcb, vtb, Mrows, 3 * Cq, Cq);
    // attention: k-split 1 (R15) — normalized output written directly, no combine
    attn_kernel<<<dim3(32, 32), 256, 0, stream>>>(qcb, kcb, vtb, aob);
    // output projection + bias: BM=64, grid 8x64 = 512 blocks = 2/CU (best measured)
    gemm_bt<64, 1><<<dim3(8, 64), 256, 0, stream>>>(aob, wprojb, (void*)out, bproj,
                                                    nullptr, nullptr, nullptr, Mrows, Cq, Cq);
}

// Round 9
// 162.962 us; speedup vs baseline: 1.1048x; 1.0299x over previous
//
#include <hip/hip_runtime.h>
#include <cstdint>
#include <cstddef>

// ---------- types ----------
typedef __bf16 bf16_t;
typedef __bf16 bf16x8 __attribute__((ext_vector_type(8)));
typedef __bf16 bf16x4 __attribute__((ext_vector_type(4)));
typedef float  f32x4  __attribute__((ext_vector_type(4)));
typedef unsigned int u32x2 __attribute__((ext_vector_type(2)));
typedef unsigned int u32x4 __attribute__((ext_vector_type(4)));

#define MFMA_BF16(a, b, c) __builtin_amdgcn_mfma_f32_16x16x32_bf16((a), (b), (c), 0, 0, 0)

// async global->LDS, 16B per lane. LDS dest must be wave-uniform base + lane*16.
__device__ __forceinline__ void async_load16(const void* g, void* l) {
    __builtin_amdgcn_global_load_lds((const __attribute__((address_space(1))) void*)g,
                                     (__attribute__((address_space(3))) void*)l,
                                     16, 0, 0);
}

// XOR-swizzled LDS layout for tiles with 8 16B-chunks per row (64 bf16/row).
// chunk (r, cg) lives at slot r*8 + (cg ^ (r&7)); returns bf16 element offset.
#define SWZ(r, cg) ((((r) << 3) | ((cg) ^ ((r) & 7))) << 3)

// ---------- problem constants ----------
#define Bq   2
#define Tq   2048
#define Cq   1024
#define Hq   16
#define HSq  64
#define Mrows 4096   // B*T

// softplus scale folded into Q at the gemm1 epilogue: 0.125 * log2(e)
#define QSCALE 0.18033688f

// ---------- fused fp32 -> bf16 convert for x, W_qkv, W_proj ----------
__global__ __launch_bounds__(256)
void cvt_all(const float* __restrict__ x, const float* __restrict__ wqkv,
             const float* __restrict__ wproj,
             bf16_t* __restrict__ xb, bf16_t* __restrict__ wqkvb,
             bf16_t* __restrict__ wprojb) {
    size_t gid = (size_t)blockIdx.x * 256 + threadIdx.x;  // quad index
    const float* src; bf16_t* dst; size_t off;
    if (gid < 1048576)      { src = x;     dst = xb;     off = gid; }
    else if (gid < 1835008) { src = wqkv;  dst = wqkvb;  off = gid - 1048576; }
    else                    { src = wproj; dst = wprojb; off = gid - 1835008; }
    float4 v = ((const float4*)src)[off];
    bf16x4 o;
    o[0] = (bf16_t)v.x; o[1] = (bf16_t)v.y; o[2] = (bf16_t)v.z; o[3] = (bf16_t)v.w;
    *(bf16x4*)(dst + off * 4) = o;
}

// ---------- GEMM: C[m][n] = sum_k A[m][k]*B[n][k], A:[M,K], B:[N,K] row-major ----------
// BK=64, XOR-swizzled LDS. EPI=1: fp32 out + bias. EPI=2: QKV split epilogue.
// R10/R13: keep >= 2 co-resident blocks/CU (1/CU exposes the barrier drain).
// R16 XCD homing (XCD = linear bid % 8):
//  MAP=1 (gemm1, 24x32 n-m grid): naive map gives XCD = n-tile%8 -> every XCD
//    reads ALL of A (8MB) = 64MB HBM fetch. Chunked remap: XCD p owns an 8m x 12n
//    rectangle -> 2MB A resident in its L2, A-fetch 64->16MB, staged loads L2-hit
//    (shortens the per-K-step vmcnt(0) drain).
//  MAP=2 (gemm2): grid (64,8), m-tile = blockIdx.x -> XCD = m-tile%8 -> 8 A-panels
//    (1MB) resident/XCD. A-fetch 64->8MB (aob is dirty-remote: these were slow
//    LLC-snoop loads sitting in the drain), B 2->16MB streaming.
template <int BM, int EPI, int MAP>
__global__ __launch_bounds__(256)
void gemm_bt(const bf16_t* __restrict__ A, const bf16_t* __restrict__ B,
             void* __restrict__ Cout, const float* __restrict__ bias,
             bf16_t* __restrict__ qc, bf16_t* __restrict__ kc, bf16_t* __restrict__ vtp,
             int M, int N, int K) {
    constexpr int MR = BM / 32;        // MFMA row-tiles per wave
    constexpr int ACH = BM * 8 / 256;  // A-chunks per thread (BM=128 -> 4, 64 -> 2)
    __shared__ __align__(16) bf16_t As[BM * 64];
    __shared__ __align__(16) bf16_t Bs[128 * 64];

    const int tid  = threadIdx.x;
    const int wave = tid >> 6;
    const int lane = tid & 63;
    int m0, n0;
    if constexpr (MAP == 1) {
        // bijective 8-XCD chunk map for a 24(n) x 32(m) tile grid, 96 blocks/XCD:
        // XCD p -> rectangle m-tiles [ (p>>1)*8, +8 ), n-tiles [ (p&1)*12, +12 )
        const int bid = blockIdx.x + gridDim.x * blockIdx.y;
        const int p = bid & 7, i = bid >> 3;
        m0 = ((p >> 1) * 8 + (i & 7)) * BM;
        n0 = ((p & 1) * 12 + (i >> 3)) * 128;
    } else if constexpr (MAP == 2) {
        m0 = blockIdx.x * BM;          // XCD = m-tile % 8
        n0 = blockIdx.y * 128;
    } else {
        m0 = blockIdx.y * BM;
        n0 = blockIdx.x * 128;
    }
    const int wm = (wave >> 1) * (BM / 2);
    const int wn = (wave & 1) * 64;
    const int lrow = lane & 15;
    const int lg   = lane >> 4;

    f32x4 acc[MR][4] = {};

    const bf16_t* Ag = A + (size_t)m0 * K;
    const bf16_t* Bg = B + (size_t)n0 * K;

    for (int k0 = 0; k0 < K; k0 += 64) {
        #pragma unroll
        for (int i = 0; i < ACH; i++) {
            int s = i * 256 + tid;
            int r = s >> 3, cg = (s & 7) ^ (r & 7);
            async_load16(Ag + (size_t)r * K + k0 + cg * 8, &As[s * 8]);
        }
        #pragma unroll
        for (int i = 0; i < 4; i++) {
            int s = i * 256 + tid;
            int r = s >> 3, cg = (s & 7) ^ (r & 7);
            async_load16(Bg + (size_t)r * K + k0 + cg * 8, &Bs[s * 8]);
        }
        __syncthreads();

        #pragma unroll
        for (int kk = 0; kk < 2; kk++) {
            bf16x8 af[MR], bfr[4];
            #pragma unroll
            for (int r = 0; r < MR; r++)
                af[r] = *(const bf16x8*)&As[SWZ(wm + r * 16 + lrow, kk * 4 + lg)];
            #pragma unroll
            for (int c = 0; c < 4; c++)
                bfr[c] = *(const bf16x8*)&Bs[SWZ(wn + c * 16 + lrow, kk * 4 + lg)];
            #pragma unroll
            for (int r = 0; r < MR; r++)
                #pragma unroll
                for (int c = 0; c < 4; c++)
                    acc[r][c] = MFMA_BF16(af[r], bfr[c], acc[r][c]);
        }
        __syncthreads();
    }

    const int er = (lane >> 4) * 4;
    const int ec = lane & 15;
    #pragma unroll
    for (int r = 0; r < MR; r++) {
        #pragma unroll
        for (int c = 0; c < 4; c++) {
            int m = m0 + wm + r * 16 + er;
            int n = n0 + wn + c * 16 + ec;
            if (EPI == 1) {
                #pragma unroll
                for (int v = 0; v < 4; v++)
                    ((float*)Cout)[(size_t)(m + v) * N + n] = acc[r][c][v] + bias[n];
            } else {
                int bb = m >> 11, t = m & 2047;   // block-uniform region (n0 128-aligned)
                if (n < 1024) {
                    // pre-scale Q so attn's S == t directly (log2-domain softplus)
                    #pragma unroll
                    for (int v = 0; v < 4; v++)
                        qc[(size_t)(m + v) * 1024 + n] = (bf16_t)(acc[r][c][v] * QSCALE);
                } else if (n < 2048) {
                    int h = (n - 1024) >> 6, d = (n - 1024) & 63;
                    bf16_t* p = kc + ((size_t)(bb * 16 + h) * Tq + t) * 64 + d;
                    #pragma unroll
                    for (int v = 0; v < 4; v++) p[v * 64] = (bf16_t)acc[r][c][v];
                } else {
                    int h = (n - 2048) >> 6, d = (n - 2048) & 63;
                    bf16x4 o;
                    #pragma unroll
                    for (int v = 0; v < 4; v++) o[v] = (bf16_t)acc[r][c][v];
                    *(bf16x4*)&vtp[((size_t)(bb * 16 + h) * 64 + d) * Tq + t] = o;
                }
            }
        }
    }
}

// ---------- attention: R6 dataflow, k-split 1 (R15) ----------
// R8: grid (bh, qi) -> XCD = bh%8 owns 4 bh = 2MB K/V (L2-resident); log2-softplus.
// R9..R12: dbuf single-barrier + permlane W redistribution (neutral; kept).
// R14/R15 confirmed the traffic model: one block owns a full q-row -> full n2
// in-block -> normalized output written DIRECTLY (no partials, no combine).
__global__ __launch_bounds__(256)
void attn_kernel(const bf16_t* __restrict__ Qc, const bf16_t* __restrict__ Kc,
                 const bf16_t* __restrict__ Vt, bf16_t* __restrict__ ao) {
    __shared__ __align__(16) bf16_t Ks[2][64 * 64];  // swizzled [key][d], double-buffered
    __shared__ __align__(16) bf16_t Vs[2][64 * 64];  // swizzled [d][key], double-buffered

    const int tid = threadIdx.x;
    const int wave = tid >> 6;
    const int lane = tid & 63;
    const int lrow = lane & 15;
    const int lg   = lane >> 4;     // 0..3
    const int er = lg * 4;
    const int ec = lane & 15;

    const int qi = 31 - blockIdx.y;       // heavy-first
    const int q0 = qi * 64;
    const int bh = blockIdx.x;            // XCD = bh % 8 -> per-XCD K/V = 4 bh = 2MB
    const int b = bh >> 4, h = bh & 15;

    const int hi = qi + 1;                // tiles 0..qi inclusive

    const bf16_t* Qb = Qc + (size_t)b * Tq * Cq + h * 64;
    const bf16_t* Kb = Kc + (size_t)bh * Tq * 64;
    const bf16_t* Vb = Vt + (size_t)bh * 64 * Tq;

    // Q fragments (B-operand for S^T); Q is pre-scaled by 0.125*log2e
    bf16x8 qf[2];
    {
        const bf16_t* qrow = Qb + (size_t)(q0 + wave * 16 + lrow) * Cq + lg * 8;
        qf[0] = *(const bf16x8*)(qrow);
        qf[1] = *(const bf16x8*)(qrow + 32);
    }

    // staging slots (swizzled): thread covers slots tid and tid+256
    const int s0 = tid, s1 = tid + 256;
    const int r0 = s0 >> 3, cg0 = (s0 & 7) ^ (r0 & 7);
    const int r1 = s1 >> 3, cg1 = (s1 & 7) ^ (r1 & 7);

    bf16x8 kr0, kr1, vr0, vr1;
    {
        kr0 = *(const bf16x8*)&Kb[(size_t)r0 * 64 + cg0 * 8];
        kr1 = *(const bf16x8*)&Kb[(size_t)r1 * 64 + cg1 * 8];
        vr0 = *(const bf16x8*)&Vb[(size_t)r0 * Tq + cg0 * 8];
        vr1 = *(const bf16x8*)&Vb[(size_t)r1 * Tq + cg1 * 8];
    }

    f32x4 oacc[4] = {};
    float n2a = 0.f, n2b = 0.f;
    int cur = 0;

    for (int kt = 0; kt < hi; kt++) {
        // write the prefetched tile into buf cur (compiler inserts vmcnt wait here)
        bf16_t* ksp = Ks[cur];
        bf16_t* vsp = Vs[cur];
        *(bf16x8*)&ksp[s0 * 8] = kr0;
        *(bf16x8*)&ksp[s1 * 8] = kr1;
        *(bf16x8*)&vsp[s0 * 8] = vr0;
        *(bf16x8*)&vsp[s1 * 8] = vr1;

        if (kt + 1 < hi) {  // issue next prefetch; in flight during compute below
            const int k1 = (kt + 1) * 64;
            kr0 = *(const bf16x8*)&Kb[(size_t)(k1 + r0) * 64 + cg0 * 8];
            kr1 = *(const bf16x8*)&Kb[(size_t)(k1 + r1) * 64 + cg1 * 8];
            vr0 = *(const bf16x8*)&Vb[(size_t)r0 * Tq + k1 + cg0 * 8];
            vr1 = *(const bf16x8*)&Vb[(size_t)r1 * Tq + k1 + cg1 * 8];
        }

        __syncthreads();  // writes of buf cur visible; single barrier per tile

        // S^T = K Q^T : C-layout gives lane 4 consecutive KEYS (rows) for one q (col)
        f32x4 sacc[4];
        #pragma unroll
        for (int j = 0; j < 4; j++) {
            int r = j * 16 + lrow;
            bf16x8 kf0 = *(const bf16x8*)&ksp[SWZ(r, lg)];
            bf16x8 kf1 = *(const bf16x8*)&ksp[SWZ(r, 4 + lg)];
            f32x4 z = {};
            z = MFMA_BF16(kf0, qf[0], z);
            sacc[j] = MFMA_BF16(kf1, qf[1], z);
        }

        // log2-domain softplus, Q pre-scaled: w = log2(1 + 2^s). |s| <~ 9, no overflow.
        // pk[j] = {pack01, pack23}: keys j*16+er+{0,1} and +{2,3} for q = wave*16+ec.
        const bool diag = (kt == qi);  // wave-uniform branch
        uint32_t pk[4][2];
        #pragma unroll
        for (int j = 0; j < 4; j++) {
            bf16x4 wb;
            #pragma unroll
            for (int v = 0; v < 4; v++) {
                float u = __builtin_amdgcn_exp2f(sacc[j][v]);
                float w = __builtin_amdgcn_logf(1.f + u);  // v_log = log2
                if (diag && (j * 16 + er + v > wave * 16 + ec)) w = 0.f;   // key > q
                if (j & 1) n2b += w * w; else n2a += w * w;
                wb[v] = (bf16_t)w;
            }
            u32x2 pw = *(u32x2*)&wb;
            pk[j][0] = pw.x; pk[j][1] = pw.y;
        }

        // O += W V, W redistributed in-register (no LDS round-trip).
        #pragma unroll
        for (int s2 = 0; s2 < 2; s2++) {
            u32x2 t0 = __builtin_amdgcn_permlane32_swap(pk[2 * s2][0], pk[2 * s2 + 1][0],
                                                        false, false);
            u32x2 w02 = __builtin_amdgcn_permlane16_swap(t0.x, t0.y, false, false);
            u32x2 t1 = __builtin_amdgcn_permlane32_swap(pk[2 * s2][1], pk[2 * s2 + 1][1],
                                                        false, false);
            u32x2 w13 = __builtin_amdgcn_permlane16_swap(t1.x, t1.y, false, false);
            u32x4 ww = {w02.x, w13.x, w02.y, w13.y};  // keys {0,1},{2,3},{4,5},{6,7} + lg*8
            bf16x8 wf = *(bf16x8*)&ww;
            #pragma unroll
            for (int jd = 0; jd < 4; jd++) {
                bf16x8 vf = *(const bf16x8*)&vsp[SWZ(jd * 16 + lrow, s2 * 4 + lg)];
                oacc[jd] = MFMA_BF16(wf, vf, oacc[jd]);
            }
        }
        cur ^= 1;
    }

    // n2 per lane covers q = wave*16+ec; reduce over the 4 lane-groups -> lg-uniform
    float n2 = n2a + n2b;
    n2 += __shfl_xor(n2, 16, 64);
    n2 += __shfl_xor(n2, 32, 64);

    // normalized output, written directly to attention-out [B,T,C] (no partials).
    // lane writes rows wave*16+er+v; its n2 is for q=wave*16+ec -> gather the row's
    // norm via shfl width16 from the lane with ec == er+v (n2 is lg-uniform).
    bf16_t* aop = ao + ((size_t)(b * Tq + q0 + wave * 16) * Cq) + h * HSq;
    #pragma unroll
    for (int v = 0; v < 4; v++) {
        float inv = rsqrtf(__shfl(n2, er + v, 16));
        #pragma unroll
        for (int jd = 0; jd < 4; jd++) {
            aop[(size_t)(er + v) * Cq + jd * 16 + ec] = (bf16_t)(oacc[jd][v] * inv);
        }
    }
}

// ---------- launch ----------
extern "C" void kernel_launch(void* const* d_in, const int* in_sizes, int n_in,
                              void* d_out, int out_size, void* d_ws, size_t ws_size,
                              hipStream_t stream) {
    const float* x     = (const float*)d_in[0];
    const float* wqkv  = (const float*)d_in[1];
    const float* wproj = (const float*)d_in[2];
    const float* bproj = (const float*)d_in[3];
    float* out = (float*)d_out;

    // workspace lifetime plan (64 MB):
    //  phase1 cvt+gemm1: wprojb[0,2) xb[2,10) wqkvb[10,16) qcb[16,24) kcb[24,32) vtb[32,40)
    //  phase2 attn:      reads qcb/kcb/vtb, writes ao over dead xb[2,10)
    //  phase3 gemm2:     reads ao[2,10) + wprojb[0,2)
    char* ws = (char*)d_ws;
    bf16_t* wprojb = (bf16_t*)(ws);
    bf16_t* xb     = (bf16_t*)(ws + ( 2u << 20));
    bf16_t* wqkvb  = (bf16_t*)(ws + (10u << 20));
    bf16_t* qcb    = (bf16_t*)(ws + (16u << 20));
    bf16_t* kcb    = (bf16_t*)(ws + (24u << 20));
    bf16_t* vtb    = (bf16_t*)(ws + (32u << 20));
    bf16_t* aob    = (bf16_t*)(ws + ( 2u << 20));  // over dead xb

    cvt_all<<<8192, 256, 0, stream>>>(x, wqkv, wproj, xb, wqkvb, wprojb);

    // QKV projection with fused layout epilogue: Qc (pre-scaled) / Kc / V^T
    // MAP=1: chunked XCD remap (A-panels L2-resident, A-fetch 64->16MB)
    gemm_bt<128, 2, 1><<<dim3(24, 32), 256, 0, stream>>>(xb, wqkvb, nullptr, nullptr,
                                                         qcb, kcb, vtb, Mrows, 3 * Cq, Cq);
    // attention: k-split 1 (R15) — normalized output written directly, no combine
    attn_kernel<<<dim3(32, 32), 256, 0, stream>>>(qcb, kcb, vtb, aob);
    // output projection + bias: BM=64, 512 blocks = 2/CU; MAP=2 grid (64m, 8n):
    // XCD = m-tile%8 -> aob panels fetched once (A-fetch 64->8MB)
    gemm_bt<64, 1, 2><<<dim3(64, 8), 256, 0, stream>>>(aob, wprojb, (void*)out, bproj,
                                                       nullptr, nullptr, nullptr, Mrows, Cq, Cq);
}